// Round 1
// baseline (2809.516 us; speedup 1.0000x reference)
//
#include <hip/hip_runtime.h>
#include <stddef.h>

// ---------------------------------------------------------------------------
// GNN-BiLSTM, all-f32 baseline.
//   x[32,64,168] -> masked GEMM1+ReLU -> [2048,1792]
//                -> masked GEMM2+ReLU -> [2048,3584]   (rows r = b*64 + t)
//                -> xproj_f / xproj_b (+combined bias) -> [2048,2048] each
//                -> 64 sequential BiLSTM step kernels (both dirs fused)
//                -> y[32,64,1024] -> GEMM+ReLU -> [2048,256] -> GEMM -> out
// Outputs concat: out(524288) | hidden(2*32*512) | cell(2*32*512)
// ---------------------------------------------------------------------------

// ---------------- generic tiled f32 GEMM: C = act(A @ W^T + bias) ----------
// A[M][K], W[N][K] (optionally elementwise-masked), bias[N], C[M][N]
// Requires: M % BM == 0, N % BN == 0, K % 4 == 0.
template<int BM, int BN, int BK, int TM, int TN, bool MASK, bool RELU>
__global__ __launch_bounds__(256)
void gemm_bt(const float* __restrict__ A, const float* __restrict__ W,
             const float* __restrict__ Msk, const float* __restrict__ bias,
             float* __restrict__ C, int M, int N, int K)
{
    __shared__ float As[BK][BM + 4];
    __shared__ float Ws[BK][BN + 4];
    const int tid = threadIdx.x;
    const int n0 = blockIdx.x * BN;
    const int m0 = blockIdx.y * BM;
    constexpr int NTX = BN / TN;
    const int tx = tid % NTX;
    const int ty = tid / NTX;

    float acc[TM][TN];
#pragma unroll
    for (int i = 0; i < TM; ++i)
#pragma unroll
        for (int j = 0; j < TN; ++j) acc[i][j] = 0.f;

    constexpr int KF4 = BK / 4;

    for (int kt = 0; kt < K; kt += BK) {
        // stage A tile (transposed into [k][m])
        for (int i = tid; i < BM * KF4; i += 256) {
            int row = i / KF4;
            int c4  = (i % KF4) * 4;
            int gk  = kt + c4;
            float4 v = make_float4(0.f, 0.f, 0.f, 0.f);
            if (gk < K) v = *(const float4*)&A[(size_t)(m0 + row) * K + gk];
            As[c4 + 0][row] = v.x; As[c4 + 1][row] = v.y;
            As[c4 + 2][row] = v.z; As[c4 + 3][row] = v.w;
        }
        // stage W tile (transposed into [k][n]), mask folded in
        for (int i = tid; i < BN * KF4; i += 256) {
            int row = i / KF4;
            int c4  = (i % KF4) * 4;
            int gk  = kt + c4;
            float4 v = make_float4(0.f, 0.f, 0.f, 0.f);
            if (gk < K) {
                v = *(const float4*)&W[(size_t)(n0 + row) * K + gk];
                if (MASK) {
                    float4 m = *(const float4*)&Msk[(size_t)(n0 + row) * K + gk];
                    v.x *= m.x; v.y *= m.y; v.z *= m.z; v.w *= m.w;
                }
            }
            Ws[c4 + 0][row] = v.x; Ws[c4 + 1][row] = v.y;
            Ws[c4 + 2][row] = v.z; Ws[c4 + 3][row] = v.w;
        }
        __syncthreads();

#pragma unroll
        for (int k = 0; k < BK; ++k) {
            float av[TM], wv[TN];
#pragma unroll
            for (int i = 0; i < TM; i += 4)
                *(float4*)&av[i] = *(const float4*)&As[k][ty * TM + i];
#pragma unroll
            for (int j = 0; j < TN; j += 4)
                *(float4*)&wv[j] = *(const float4*)&Ws[k][tx * TN + j];
#pragma unroll
            for (int i = 0; i < TM; ++i)
#pragma unroll
                for (int j = 0; j < TN; ++j)
                    acc[i][j] = fmaf(av[i], wv[j], acc[i][j]);
        }
        __syncthreads();
    }

    // epilogue: bias + optional relu, float4 stores
#pragma unroll
    for (int i = 0; i < TM; ++i) {
        int m = m0 + ty * TM + i;
#pragma unroll
        for (int j = 0; j < TN; j += 4) {
            int n = n0 + tx * TN + j;
            float4 v;
            v.x = acc[i][j + 0] + bias[n + 0];
            v.y = acc[i][j + 1] + bias[n + 1];
            v.z = acc[i][j + 2] + bias[n + 2];
            v.w = acc[i][j + 3] + bias[n + 3];
            if (RELU) {
                v.x = fmaxf(v.x, 0.f); v.y = fmaxf(v.y, 0.f);
                v.z = fmaxf(v.z, 0.f); v.w = fmaxf(v.w, 0.f);
            }
            *(float4*)&C[(size_t)m * N + n] = v;
        }
    }
}

// ---------------- combined LSTM biases: bsum = b_ih + b_hh (both dirs) -----
__global__ void bias_sum_kernel(const float* __restrict__ bihf, const float* __restrict__ bhhf,
                                const float* __restrict__ bihb, const float* __restrict__ bhhb,
                                float* __restrict__ o)
{
    int i = blockIdx.x * blockDim.x + threadIdx.x;
    if (i < 2048)      o[i] = bihf[i] + bhhf[i];
    else if (i < 4096) o[i] = bihb[i - 2048] + bhhb[i - 2048];
}

// ---------------- one BiLSTM time step (both directions) -------------------
// grid = 256 blocks: dir = bid>>7, j-tile (4 j's) = bid&127. block = 256 thr.
// Per block: gates (4 groups x 4 j x 32 b), K=512 dot vs LDS-staged h.
// h ping-pong: read hbuf[dir][t&1], write hbuf[dir][(t+1)&1] (cross-block
// safe: all blocks read the full previous-h before anyone's write matters
// only in the NEXT launch). c is owned per-(b,j)-thread, no aliasing.
__global__ __launch_bounds__(256)
void lstm_step(int t,
               const float* __restrict__ xpf, const float* __restrict__ xpb,
               const float* __restrict__ whh_f, const float* __restrict__ whh_b,
               float* __restrict__ hbuf,   // [2][2][32*512]
               float* __restrict__ cbuf,   // [2][32*512]
               float* __restrict__ y,      // [32][64][1024]
               float* __restrict__ out)    // d_out (hidden/cell at t==63)
{
    __shared__ float hT[256 * 32];   // [k_local][b]   32 KB
    __shared__ float wS[16][256];    // 16 gate rows   16 KB
    __shared__ float gbuf[16 * 32];  // [gi*4+jl][b]    2 KB

    const int bid = blockIdx.x;
    const int dir = bid >> 7;
    const int jt  = bid & 127;
    const int j0  = jt * 4;
    const int tid = threadIdx.x;

    const float* xp  = dir ? xpb : xpf;
    const float* whh = dir ? whh_b : whh_f;
    const int tt = dir ? (63 - t) : t;

    float* hread  = hbuf + dir * 2 * 16384 + (t & 1) * 16384;
    float* hwrite = hbuf + dir * 2 * 16384 + ((t + 1) & 1) * 16384;
    float* cst    = cbuf + dir * 16384;

    const int b = tid & 31;
    const int q = tid >> 5;           // 0..7
    const int gi = q >> 1;            // gate group 0..3
    const int jh = q & 1;             // which j-pair
    const int r1 = gi * 4 + jh * 2;
    const int r2 = r1 + 1;

    float acc1 = 0.f, acc2 = 0.f;

    for (int kh = 0; kh < 2; ++kh) {
        // ---- stage h transposed: thread (b, ks) covers 32 k's ----
        {
            const int ks = q;  // 0..7
            const float* hrow = hread + b * 512 + kh * 256 + ks * 32;
#pragma unroll
            for (int u = 0; u < 8; ++u) {
                float4 v = *(const float4*)&hrow[u * 4];
                int k = ks * 32 + u * 4;
                hT[(k + 0) * 32 + b] = v.x;
                hT[(k + 1) * 32 + b] = v.y;
                hT[(k + 2) * 32 + b] = v.z;
                hT[(k + 3) * 32 + b] = v.w;
            }
        }
        // ---- stage 16 w_hh rows (this half of K) ----
        for (int i = tid; i < 1024; i += 256) {   // 1024 float4s
            int r  = i >> 6;          // 0..15
            int c4 = (i & 63) * 4;    // 0..252
            int gr = (r >> 2) * 512 + j0 + (r & 3);
            float4 v = *(const float4*)&whh[(size_t)gr * 512 + kh * 256 + c4];
            *(float4*)&wS[r][c4] = v;
        }
        __syncthreads();

        // ---- dot: 2 outputs per thread over this K-half ----
#pragma unroll 4
        for (int kc = 0; kc < 64; ++kc) {
            float4 w1v = *(const float4*)&wS[r1][kc * 4];
            float4 w2v = *(const float4*)&wS[r2][kc * 4];
            float h0 = hT[(kc * 4 + 0) * 32 + b];
            float h1 = hT[(kc * 4 + 1) * 32 + b];
            float h2 = hT[(kc * 4 + 2) * 32 + b];
            float h3 = hT[(kc * 4 + 3) * 32 + b];
            acc1 = fmaf(h0, w1v.x, acc1); acc1 = fmaf(h1, w1v.y, acc1);
            acc1 = fmaf(h2, w1v.z, acc1); acc1 = fmaf(h3, w1v.w, acc1);
            acc2 = fmaf(h0, w2v.x, acc2); acc2 = fmaf(h1, w2v.y, acc2);
            acc2 = fmaf(h2, w2v.z, acc2); acc2 = fmaf(h3, w2v.w, acc2);
        }
        __syncthreads();   // before restaging LDS next half
    }

    gbuf[r1 * 32 + b] = acc1;
    gbuf[r2 * 32 + b] = acc2;
    __syncthreads();

    // ---- gate math + state update: 128 threads own (b, jl) ----
    if (tid < 128) {
        const int b2 = tid & 31;
        const int jl = tid >> 5;        // 0..3
        const int j  = j0 + jl;
        const float* xprow = xp + ((size_t)(b2 * 64 + tt)) * 2048;
        float g_i = gbuf[(0 * 4 + jl) * 32 + b2] + xprow[0 * 512 + j];
        float g_f = gbuf[(1 * 4 + jl) * 32 + b2] + xprow[1 * 512 + j];
        float g_g = gbuf[(2 * 4 + jl) * 32 + b2] + xprow[2 * 512 + j];
        float g_o = gbuf[(3 * 4 + jl) * 32 + b2] + xprow[3 * 512 + j];

        float si = 1.f / (1.f + expf(-g_i));
        float sf = 1.f / (1.f + expf(-g_f));
        float so = 1.f / (1.f + expf(-g_o));
        float tg = tanhf(g_g);

        float c_old = cst[b2 * 512 + j];
        float c_new = sf * c_old + si * tg;
        float h_new = so * tanhf(c_new);

        cst[b2 * 512 + j]    = c_new;
        hwrite[b2 * 512 + j] = h_new;
        y[((size_t)b2 * 64 + tt) * 1024 + dir * 512 + j] = h_new;

        if (t == 63) {   // final states: fwd after t=63, bwd after tb=0
            out[524288 + dir * 16384 + b2 * 512 + j]         = h_new;  // hidden
            out[524288 + 32768 + dir * 16384 + b2 * 512 + j] = c_new;  // cell
        }
    }
}

// ---------------------------------------------------------------------------
extern "C" void kernel_launch(void* const* d_in, const int* in_sizes, int n_in,
                              void* d_out, int out_size, void* d_ws, size_t ws_size,
                              hipStream_t stream)
{
    const float* x     = (const float*)d_in[0];
    const float* w1    = (const float*)d_in[1];
    const float* b1    = (const float*)d_in[2];
    const float* mask1 = (const float*)d_in[3];
    const float* w2    = (const float*)d_in[4];
    const float* b2    = (const float*)d_in[5];
    const float* mask2 = (const float*)d_in[6];
    const float* wihf  = (const float*)d_in[7];
    const float* whhf  = (const float*)d_in[8];
    const float* bihf  = (const float*)d_in[9];
    const float* bhhf  = (const float*)d_in[10];
    const float* wihb  = (const float*)d_in[11];
    const float* whhb  = (const float*)d_in[12];
    const float* bihb  = (const float*)d_in[13];
    const float* bhhb  = (const float*)d_in[14];
    const float* wo1   = (const float*)d_in[15];
    const float* bo1   = (const float*)d_in[16];
    const float* wo2   = (const float*)d_in[17];
    const float* bo2   = (const float*)d_in[18];
    float* out = (float*)d_out;

    // ---- workspace layout (floats) ----
    float* ws   = (float*)d_ws;
    float* h1   = ws;                    // 2048*1792 = 3,670,016
    float* h2   = h1 + 3670016;          // 2048*3584 = 7,340,032
    float* xpf  = h2 + 7340032;          // 2048*2048 = 4,194,304
    float* xpb  = xpf + 4194304;         // 4,194,304
    float* hbuf = xpb + 4194304;         // 2 dirs * 2 bufs * 16384 = 65,536
    float* cbuf = hbuf + 65536;          // 2 * 16384 = 32,768
    float* bsum = cbuf + 32768;          // 4,096
    float* ybuf = bsum + 4096;           // 32*64*1024 = 2,097,152
    float* o1   = ybuf + 2097152;        // 2048*256 = 524,288
    // total ~22.1M floats (~88.5 MB)

    // zero-init h ping-pong + c (contiguous region)
    hipMemsetAsync(hbuf, 0, (size_t)(65536 + 32768) * sizeof(float), stream);

    bias_sum_kernel<<<16, 256, 0, stream>>>(bihf, bhhf, bihb, bhhb, bsum);

    // GEMM1: [2048,168] x (w1*mask1)[1792,168]^T + b1, ReLU
    gemm_bt<64, 64, 16, 4, 4, true, true><<<dim3(1792 / 64, 2048 / 64), 256, 0, stream>>>(
        x, w1, mask1, b1, h1, 2048, 1792, 168);

    // GEMM2: [2048,1792] x (w2*mask2)[3584,1792]^T + b2, ReLU
    gemm_bt<128, 128, 16, 8, 8, true, true><<<dim3(3584 / 128, 2048 / 128), 256, 0, stream>>>(
        h1, w2, mask2, b2, h2, 2048, 3584, 1792);

    // LSTM input projections (+combined bias), both directions
    gemm_bt<128, 128, 16, 8, 8, false, false><<<dim3(2048 / 128, 2048 / 128), 256, 0, stream>>>(
        h2, wihf, nullptr, bsum, xpf, 2048, 2048, 3584);
    gemm_bt<128, 128, 16, 8, 8, false, false><<<dim3(2048 / 128, 2048 / 128), 256, 0, stream>>>(
        h2, wihb, nullptr, bsum + 2048, xpb, 2048, 2048, 3584);

    // 64 sequential BiLSTM steps (fwd t, bwd 63-t fused per launch)
    for (int t = 0; t < 64; ++t)
        lstm_step<<<256, 256, 0, stream>>>(t, xpf, xpb, whhf, whhb,
                                           hbuf, cbuf, ybuf, out);

    // output head: ReLU(y @ wo1^T + bo1) @ wo2^T + bo2
    gemm_bt<64, 64, 16, 4, 4, false, true><<<dim3(256 / 64, 2048 / 64), 256, 0, stream>>>(
        ybuf, wo1, nullptr, bo1, o1, 2048, 256, 1024);
    gemm_bt<64, 64, 16, 4, 4, false, false><<<dim3(256 / 64, 2048 / 64), 256, 0, stream>>>(
        o1, wo2, nullptr, bo2, out, 2048, 256, 256);
}

// Round 2
// 1293.243 us; speedup vs baseline: 2.1725x; 2.1725x over previous
//
#include <hip/hip_runtime.h>
#include <stddef.h>

typedef float f32x4 __attribute__((ext_vector_type(4)));
typedef short s16x8 __attribute__((ext_vector_type(8)));

__device__ __forceinline__ short f2bf(float f) {
    unsigned u = __float_as_uint(f);
    unsigned r = (u + 0x7fffu + ((u >> 16) & 1u)) >> 16;   // RNE
    return (short)r;
}

__device__ __forceinline__ void load_lds16(const void* g, void* l) {
    __builtin_amdgcn_global_load_lds(
        (const __attribute__((address_space(1))) unsigned int*)g,
        (__attribute__((address_space(3))) unsigned int*)l, 16, 0, 0);
}

// ---------------- bf16 MFMA GEMM: C = act(A @ W^T + bias) ------------------
// A[M][K] bf16, W[N][K] bf16 (row-major, K contiguous), bias[N] f32.
// 128x128 tile, BK=64, 256 threads = 4 waves (2x2), each wave 64x64.
// LDS linear [128][64] bf16 per operand; XOR swizzle slot^=(row&7) applied on
// BOTH the global source of global_load_lds and the ds_read side (rule #21).
// Requires M%128==0, N%128==0, K%64==0.
template<bool OBF16, bool RELU>
__global__ __launch_bounds__(256)
void gemm_mfma(const short* __restrict__ A, const short* __restrict__ W,
               const float* __restrict__ bias, void* __restrict__ Cv,
               int M, int N, int K)
{
    __shared__ short As[128 * 64];
    __shared__ short Bs[128 * 64];
    const int tid = threadIdx.x;
    const int l    = tid & 63;
    const int wave = tid >> 6;
    const int wr = wave >> 1, wc = wave & 1;
    const int n0 = blockIdx.x * 128, m0 = blockIdx.y * 128;

    f32x4 acc[4][4];
#pragma unroll
    for (int i = 0; i < 4; ++i)
#pragma unroll
        for (int j = 0; j < 4; ++j) {
            acc[i][j][0] = 0.f; acc[i][j][1] = 0.f;
            acc[i][j][2] = 0.f; acc[i][j][3] = 0.f;
        }

    // staging: call j covers rows j*32..j*32+31; thread covers 8 bf16 (16B)
    const int srow = tid >> 3;                      // 0..31 within a call
    const int gc   = (tid & 7) ^ (srow & 7);        // pre-swizzled k-chunk
    const short* gA = A + (size_t)(m0 + srow) * K + gc * 8;
    const short* gB = W + (size_t)(n0 + srow) * K + gc * 8;
    char* AsB = (char*)As;
    char* BsB = (char*)Bs;
    char* dstA = AsB + wave * 1024;
    char* dstB = BsB + wave * 1024;

    // fragment-read offsets (swizzled): row&7 == l&7 for all fragments
    int aoff[4], boff[4], soff[2];
#pragma unroll
    for (int mi = 0; mi < 4; ++mi) aoff[mi] = (wr * 64 + mi * 16 + (l & 15)) * 128;
#pragma unroll
    for (int ni = 0; ni < 4; ++ni) boff[ni] = (wc * 64 + ni * 16 + (l & 15)) * 128;
#pragma unroll
    for (int kh = 0; kh < 2; ++kh) soff[kh] = ((kh * 4 + (l >> 4)) ^ (l & 7)) * 16;

    for (int kt = 0; kt < K; kt += 64) {
#pragma unroll
        for (int j = 0; j < 4; ++j) {
            load_lds16(gA + (size_t)j * 32 * K + kt, dstA + j * 4096);
            load_lds16(gB + (size_t)j * 32 * K + kt, dstB + j * 4096);
        }
        __syncthreads();
#pragma unroll
        for (int kh = 0; kh < 2; ++kh) {
            s16x8 af[4], bfr[4];
#pragma unroll
            for (int mi = 0; mi < 4; ++mi)
                af[mi] = *(const s16x8*)(AsB + aoff[mi] + soff[kh]);
#pragma unroll
            for (int ni = 0; ni < 4; ++ni)
                bfr[ni] = *(const s16x8*)(BsB + boff[ni] + soff[kh]);
#pragma unroll
            for (int mi = 0; mi < 4; ++mi)
#pragma unroll
                for (int ni = 0; ni < 4; ++ni)
                    acc[mi][ni] = __builtin_amdgcn_mfma_f32_16x16x32_bf16(
                        af[mi], bfr[ni], acc[mi][ni], 0, 0, 0);
        }
        __syncthreads();
    }

    // epilogue: C/D layout col=lane&15, row=(lane>>4)*4+reg
    const int colf = l & 15, rowf = (l >> 4) * 4;
#pragma unroll
    for (int mi = 0; mi < 4; ++mi)
#pragma unroll
        for (int ni = 0; ni < 4; ++ni) {
            const int n = n0 + wc * 64 + ni * 16 + colf;
            const float bv = bias[n];
#pragma unroll
            for (int r = 0; r < 4; ++r) {
                const int m = m0 + wr * 64 + mi * 16 + rowf + r;
                float v = acc[mi][ni][r] + bv;
                if (RELU) v = fmaxf(v, 0.f);
                if (OBF16) ((short*)Cv)[(size_t)m * N + n] = f2bf(v);
                else       ((float*)Cv)[(size_t)m * N + n] = v;
            }
        }
}

// ---------------- f32 -> bf16 conversion (optional elementwise mask) -------
__global__ void conv_bf16(const float* __restrict__ in, const float* __restrict__ mask,
                          short* __restrict__ out, int n4)
{
    int i = blockIdx.x * blockDim.x + threadIdx.x;
    if (i >= n4) return;
    float4 v = ((const float4*)in)[i];
    if (mask) {
        float4 m = ((const float4*)mask)[i];
        v.x *= m.x; v.y *= m.y; v.z *= m.z; v.w *= m.w;
    }
    short4 o;
    o.x = f2bf(v.x); o.y = f2bf(v.y); o.z = f2bf(v.z); o.w = f2bf(v.w);
    ((short4*)out)[i] = o;
}

// ---------------- generic tiled f32 GEMM: C = act(A @ W^T + bias) ----------
template<int BM, int BN, int BK, int TM, int TN, bool MASK, bool RELU, bool OBF16>
__global__ __launch_bounds__(256)
void gemm_bt(const float* __restrict__ A, const float* __restrict__ W,
             const float* __restrict__ Msk, const float* __restrict__ bias,
             void* __restrict__ Cv, int M, int N, int K)
{
    __shared__ float As[BK][BM + 4];
    __shared__ float Ws[BK][BN + 4];
    const int tid = threadIdx.x;
    const int n0 = blockIdx.x * BN;
    const int m0 = blockIdx.y * BM;
    constexpr int NTX = BN / TN;
    const int tx = tid % NTX;
    const int ty = tid / NTX;

    float acc[TM][TN];
#pragma unroll
    for (int i = 0; i < TM; ++i)
#pragma unroll
        for (int j = 0; j < TN; ++j) acc[i][j] = 0.f;

    constexpr int KF4 = BK / 4;

    for (int kt = 0; kt < K; kt += BK) {
        for (int i = tid; i < BM * KF4; i += 256) {
            int row = i / KF4;
            int c4  = (i % KF4) * 4;
            int gk  = kt + c4;
            float4 v = make_float4(0.f, 0.f, 0.f, 0.f);
            if (gk < K) v = *(const float4*)&A[(size_t)(m0 + row) * K + gk];
            As[c4 + 0][row] = v.x; As[c4 + 1][row] = v.y;
            As[c4 + 2][row] = v.z; As[c4 + 3][row] = v.w;
        }
        for (int i = tid; i < BN * KF4; i += 256) {
            int row = i / KF4;
            int c4  = (i % KF4) * 4;
            int gk  = kt + c4;
            float4 v = make_float4(0.f, 0.f, 0.f, 0.f);
            if (gk < K) {
                v = *(const float4*)&W[(size_t)(n0 + row) * K + gk];
                if (MASK) {
                    float4 m = *(const float4*)&Msk[(size_t)(n0 + row) * K + gk];
                    v.x *= m.x; v.y *= m.y; v.z *= m.z; v.w *= m.w;
                }
            }
            Ws[c4 + 0][row] = v.x; Ws[c4 + 1][row] = v.y;
            Ws[c4 + 2][row] = v.z; Ws[c4 + 3][row] = v.w;
        }
        __syncthreads();

#pragma unroll
        for (int k = 0; k < BK; ++k) {
            float av[TM], wv[TN];
#pragma unroll
            for (int i = 0; i < TM; i += 4)
                *(float4*)&av[i] = *(const float4*)&As[k][ty * TM + i];
#pragma unroll
            for (int j = 0; j < TN; j += 4)
                *(float4*)&wv[j] = *(const float4*)&Ws[k][tx * TN + j];
#pragma unroll
            for (int i = 0; i < TM; ++i)
#pragma unroll
                for (int j = 0; j < TN; ++j)
                    acc[i][j] = fmaf(av[i], wv[j], acc[i][j]);
        }
        __syncthreads();
    }

#pragma unroll
    for (int i = 0; i < TM; ++i) {
        int m = m0 + ty * TM + i;
#pragma unroll
        for (int j = 0; j < TN; ++j) {
            int n = n0 + tx * TN + j;
            float v = acc[i][j] + bias[n];
            if (RELU) v = fmaxf(v, 0.f);
            if (OBF16) ((short*)Cv)[(size_t)m * N + n] = f2bf(v);
            else       ((float*)Cv)[(size_t)m * N + n] = v;
        }
    }
}

// ---------------- combined LSTM biases -------------------------------------
__global__ void bias_sum_kernel(const float* __restrict__ bihf, const float* __restrict__ bhhf,
                                const float* __restrict__ bihb, const float* __restrict__ bhhb,
                                float* __restrict__ o)
{
    int i = blockIdx.x * blockDim.x + threadIdx.x;
    if (i < 2048)      o[i] = bihf[i] + bhhf[i];
    else if (i < 4096) o[i] = bihb[i - 2048] + bhhb[i - 2048];
}

// ---------------- one BiLSTM time step (both directions) -------------------
__global__ __launch_bounds__(256)
void lstm_step(int t,
               const float* __restrict__ xpf, const float* __restrict__ xpb,
               const float* __restrict__ whh_f, const float* __restrict__ whh_b,
               float* __restrict__ hbuf,   // [2][2][32*512]
               float* __restrict__ cbuf,   // [2][32*512]
               float* __restrict__ y,      // [32][64][1024]
               float* __restrict__ out)    // d_out (hidden/cell at t==63)
{
    __shared__ float hT[256 * 32];
    __shared__ float wS[16][256];
    __shared__ float gbuf[16 * 32];

    const int bid = blockIdx.x;
    const int dir = bid >> 7;
    const int jt  = bid & 127;
    const int j0  = jt * 4;
    const int tid = threadIdx.x;

    const float* xp  = dir ? xpb : xpf;
    const float* whh = dir ? whh_b : whh_f;
    const int tt = dir ? (63 - t) : t;

    float* hread  = hbuf + dir * 2 * 16384 + (t & 1) * 16384;
    float* hwrite = hbuf + dir * 2 * 16384 + ((t + 1) & 1) * 16384;
    float* cst    = cbuf + dir * 16384;

    const int b = tid & 31;
    const int q = tid >> 5;
    const int gi = q >> 1;
    const int jh = q & 1;
    const int r1 = gi * 4 + jh * 2;
    const int r2 = r1 + 1;

    float acc1 = 0.f, acc2 = 0.f;

    for (int kh = 0; kh < 2; ++kh) {
        {
            const int ks = q;
            const float* hrow = hread + b * 512 + kh * 256 + ks * 32;
#pragma unroll
            for (int u = 0; u < 8; ++u) {
                float4 v = *(const float4*)&hrow[u * 4];
                int k = ks * 32 + u * 4;
                hT[(k + 0) * 32 + b] = v.x;
                hT[(k + 1) * 32 + b] = v.y;
                hT[(k + 2) * 32 + b] = v.z;
                hT[(k + 3) * 32 + b] = v.w;
            }
        }
        for (int i = tid; i < 1024; i += 256) {
            int r  = i >> 6;
            int c4 = (i & 63) * 4;
            int gr = (r >> 2) * 512 + j0 + (r & 3);
            float4 v = *(const float4*)&whh[(size_t)gr * 512 + kh * 256 + c4];
            *(float4*)&wS[r][c4] = v;
        }
        __syncthreads();

#pragma unroll 4
        for (int kc = 0; kc < 64; ++kc) {
            float4 w1v = *(const float4*)&wS[r1][kc * 4];
            float4 w2v = *(const float4*)&wS[r2][kc * 4];
            float h0 = hT[(kc * 4 + 0) * 32 + b];
            float h1 = hT[(kc * 4 + 1) * 32 + b];
            float h2 = hT[(kc * 4 + 2) * 32 + b];
            float h3 = hT[(kc * 4 + 3) * 32 + b];
            acc1 = fmaf(h0, w1v.x, acc1); acc1 = fmaf(h1, w1v.y, acc1);
            acc1 = fmaf(h2, w1v.z, acc1); acc1 = fmaf(h3, w1v.w, acc1);
            acc2 = fmaf(h0, w2v.x, acc2); acc2 = fmaf(h1, w2v.y, acc2);
            acc2 = fmaf(h2, w2v.z, acc2); acc2 = fmaf(h3, w2v.w, acc2);
        }
        __syncthreads();
    }

    gbuf[r1 * 32 + b] = acc1;
    gbuf[r2 * 32 + b] = acc2;
    __syncthreads();

    if (tid < 128) {
        const int b2 = tid & 31;
        const int jl = tid >> 5;
        const int j  = j0 + jl;
        const float* xprow = xp + ((size_t)(b2 * 64 + tt)) * 2048;
        float g_i = gbuf[(0 * 4 + jl) * 32 + b2] + xprow[0 * 512 + j];
        float g_f = gbuf[(1 * 4 + jl) * 32 + b2] + xprow[1 * 512 + j];
        float g_g = gbuf[(2 * 4 + jl) * 32 + b2] + xprow[2 * 512 + j];
        float g_o = gbuf[(3 * 4 + jl) * 32 + b2] + xprow[3 * 512 + j];

        float si = 1.f / (1.f + expf(-g_i));
        float sf = 1.f / (1.f + expf(-g_f));
        float so = 1.f / (1.f + expf(-g_o));
        float tg = tanhf(g_g);

        float c_old = cst[b2 * 512 + j];
        float c_new = sf * c_old + si * tg;
        float h_new = so * tanhf(c_new);

        cst[b2 * 512 + j]    = c_new;
        hwrite[b2 * 512 + j] = h_new;
        y[((size_t)b2 * 64 + tt) * 1024 + dir * 512 + j] = h_new;

        if (t == 63) {
            out[524288 + dir * 16384 + b2 * 512 + j]         = h_new;
            out[524288 + 32768 + dir * 16384 + b2 * 512 + j] = c_new;
        }
    }
}

// ---------------------------------------------------------------------------
extern "C" void kernel_launch(void* const* d_in, const int* in_sizes, int n_in,
                              void* d_out, int out_size, void* d_ws, size_t ws_size,
                              hipStream_t stream)
{
    const float* x     = (const float*)d_in[0];
    const float* w1    = (const float*)d_in[1];
    const float* b1    = (const float*)d_in[2];
    const float* mask1 = (const float*)d_in[3];
    const float* w2    = (const float*)d_in[4];
    const float* b2    = (const float*)d_in[5];
    const float* mask2 = (const float*)d_in[6];
    const float* wihf  = (const float*)d_in[7];
    const float* whhf  = (const float*)d_in[8];
    const float* bihf  = (const float*)d_in[9];
    const float* bhhf  = (const float*)d_in[10];
    const float* wihb  = (const float*)d_in[11];
    const float* whhb  = (const float*)d_in[12];
    const float* bihb  = (const float*)d_in[13];
    const float* bhhb  = (const float*)d_in[14];
    const float* wo1   = (const float*)d_in[15];
    const float* bo1   = (const float*)d_in[16];
    const float* wo2   = (const float*)d_in[17];
    const float* bo2   = (const float*)d_in[18];
    float* out = (float*)d_out;

    // ---- workspace layout (bytes); bf16 weight buffers alias dead regions -
    char* base = (char*)d_ws;
    float* xpf = (float*)base;                 // 16 MB  [2048x2048 f32]
    short* w2b = (short*)base;                 //   alias: 12.25 MB, dead before xpf write
    char* p1 = base + 16777216;
    float* xpb = (float*)p1;                   // 16 MB
    short* wfb = (short*)p1;                   //   alias: 14 MB, dead before xpb write
    char* p2 = p1 + 16777216;
    short* wbb = (short*)p2;                   // 14 MB   [2048x3584 bf16]
    char* p3 = p2 + 14680064;
    short* h1b = (short*)p3;                   // 7 MB    [2048x1792 bf16]
    char* p4 = p3 + 7340032;
    short* h2b = (short*)p4;                   // 14 MB   [2048x3584 bf16]
    char* p5 = p4 + 14680064;
    float* hbuf = (float*)p5;                  // 2*2*16384 f32
    float* cbuf = hbuf + 65536;                // 2*16384 f32
    float* bsum = cbuf + 32768;                // 4096 f32
    float* ybuf = bsum + 4096;                 // 32*64*1024 f32
    float* o1   = ybuf + 2097152;              // 2048*256 f32
    // total ~81.1 MB

    hipMemsetAsync(hbuf, 0, (size_t)(65536 + 32768) * sizeof(float), stream);
    bias_sum_kernel<<<16, 256, 0, stream>>>(bihf, bhhf, bihb, bhhb, bsum);

    // weight conversions to bf16
    conv_bf16<<<(6422528 / 4 + 255) / 256, 256, 0, stream>>>(w2, mask2, w2b, 6422528 / 4);
    conv_bf16<<<(7340032 / 4 + 255) / 256, 256, 0, stream>>>(wihf, nullptr, wfb, 7340032 / 4);
    conv_bf16<<<(7340032 / 4 + 255) / 256, 256, 0, stream>>>(wihb, nullptr, wbb, 7340032 / 4);

    // GEMM1 (f32 compute, bf16 out): [2048,168] x (w1*mask1)^T + b1, ReLU
    gemm_bt<64, 64, 16, 4, 4, true, true, true><<<dim3(1792 / 64, 2048 / 64), 256, 0, stream>>>(
        x, w1, mask1, b1, h1b, 2048, 1792, 168);

    // GEMM2 (bf16 MFMA): h1b x w2b^T + b2, ReLU -> h2b (bf16)
    gemm_mfma<true, true><<<dim3(3584 / 128, 2048 / 128), 256, 0, stream>>>(
        h1b, w2b, b2, h2b, 2048, 3584, 1792);

    // LSTM input projections (bf16 MFMA, f32 out, +combined bias)
    gemm_mfma<false, false><<<dim3(2048 / 128, 2048 / 128), 256, 0, stream>>>(
        h2b, wfb, bsum, xpf, 2048, 2048, 3584);
    gemm_mfma<false, false><<<dim3(2048 / 128, 2048 / 128), 256, 0, stream>>>(
        h2b, wbb, bsum + 2048, xpb, 2048, 2048, 3584);

    // 64 sequential BiLSTM steps
    for (int t = 0; t < 64; ++t)
        lstm_step<<<256, 256, 0, stream>>>(t, xpf, xpb, whhf, whhb,
                                           hbuf, cbuf, ybuf, out);

    // output head (f32)
    gemm_bt<64, 64, 16, 4, 4, false, true, false><<<dim3(256 / 64, 2048 / 64), 256, 0, stream>>>(
        ybuf, wo1, nullptr, bo1, o1, 2048, 256, 1024);
    gemm_bt<64, 64, 16, 4, 4, false, false, false><<<dim3(256 / 64, 2048 / 64), 256, 0, stream>>>(
        o1, wo2, nullptr, bo2, out, 2048, 256, 256);
}

// Round 3
// 808.246 us; speedup vs baseline: 3.4761x; 1.6001x over previous
//
#include <hip/hip_runtime.h>
#include <stddef.h>

typedef float f32x4 __attribute__((ext_vector_type(4)));
typedef short s16x8 __attribute__((ext_vector_type(8)));

__device__ __forceinline__ short f2bf(float f) {
    unsigned u = __float_as_uint(f);
    unsigned r = (u + 0x7fffu + ((u >> 16) & 1u)) >> 16;   // RNE
    return (short)r;
}

__device__ __forceinline__ void load_lds16(const void* g, void* l) {
    __builtin_amdgcn_global_load_lds(
        (const __attribute__((address_space(1))) unsigned int*)g,
        (__attribute__((address_space(3))) unsigned int*)l, 16, 0, 0);
}

// ---------------- bf16 MFMA GEMM: C = act(A @ W^T + bias) ------------------
// A[M][K] bf16, W[N][K] bf16, bias[N] f32. 128x128 tile, BK=64, 4 waves.
// Linear LDS + XOR-swizzled global source + swizzled ds_read (rule #21).
// Requires M%128==0, N%128==0, K%64==0.
template<bool OBF16, bool RELU>
__global__ __launch_bounds__(256)
void gemm_mfma(const short* __restrict__ A, const short* __restrict__ W,
               const float* __restrict__ bias, void* __restrict__ Cv,
               int M, int N, int K)
{
    __shared__ short As[128 * 64];
    __shared__ short Bs[128 * 64];
    const int tid = threadIdx.x;
    const int l    = tid & 63;
    const int wave = tid >> 6;
    const int wr = wave >> 1, wc = wave & 1;
    const int n0 = blockIdx.x * 128, m0 = blockIdx.y * 128;

    f32x4 acc[4][4];
#pragma unroll
    for (int i = 0; i < 4; ++i)
#pragma unroll
        for (int j = 0; j < 4; ++j) {
            acc[i][j][0] = 0.f; acc[i][j][1] = 0.f;
            acc[i][j][2] = 0.f; acc[i][j][3] = 0.f;
        }

    const int srow = tid >> 3;
    const int gc   = (tid & 7) ^ (srow & 7);
    const short* gA = A + (size_t)(m0 + srow) * K + gc * 8;
    const short* gB = W + (size_t)(n0 + srow) * K + gc * 8;
    char* AsB = (char*)As;
    char* BsB = (char*)Bs;
    char* dstA = AsB + wave * 1024;
    char* dstB = BsB + wave * 1024;

    int aoff[4], boff[4], soff[2];
#pragma unroll
    for (int mi = 0; mi < 4; ++mi) aoff[mi] = (wr * 64 + mi * 16 + (l & 15)) * 128;
#pragma unroll
    for (int ni = 0; ni < 4; ++ni) boff[ni] = (wc * 64 + ni * 16 + (l & 15)) * 128;
#pragma unroll
    for (int kh = 0; kh < 2; ++kh) soff[kh] = ((kh * 4 + (l >> 4)) ^ (l & 7)) * 16;

    for (int kt = 0; kt < K; kt += 64) {
#pragma unroll
        for (int j = 0; j < 4; ++j) {
            load_lds16(gA + (size_t)j * 32 * K + kt, dstA + j * 4096);
            load_lds16(gB + (size_t)j * 32 * K + kt, dstB + j * 4096);
        }
        __syncthreads();
#pragma unroll
        for (int kh = 0; kh < 2; ++kh) {
            s16x8 af[4], bfr[4];
#pragma unroll
            for (int mi = 0; mi < 4; ++mi)
                af[mi] = *(const s16x8*)(AsB + aoff[mi] + soff[kh]);
#pragma unroll
            for (int ni = 0; ni < 4; ++ni)
                bfr[ni] = *(const s16x8*)(BsB + boff[ni] + soff[kh]);
#pragma unroll
            for (int mi = 0; mi < 4; ++mi)
#pragma unroll
                for (int ni = 0; ni < 4; ++ni)
                    acc[mi][ni] = __builtin_amdgcn_mfma_f32_16x16x32_bf16(
                        af[mi], bfr[ni], acc[mi][ni], 0, 0, 0);
        }
        __syncthreads();
    }

    const int colf = l & 15, rowf = (l >> 4) * 4;
#pragma unroll
    for (int mi = 0; mi < 4; ++mi)
#pragma unroll
        for (int ni = 0; ni < 4; ++ni) {
            const int n = n0 + wc * 64 + ni * 16 + colf;
            const float bv = bias[n];
#pragma unroll
            for (int r = 0; r < 4; ++r) {
                const int m = m0 + wr * 64 + mi * 16 + rowf + r;
                float v = acc[mi][ni][r] + bv;
                if (RELU) v = fmaxf(v, 0.f);
                if (OBF16) ((short*)Cv)[(size_t)m * N + n] = f2bf(v);
                else       ((float*)Cv)[(size_t)m * N + n] = v;
            }
        }
}

// ---------------- f32 -> bf16 conversion (optional elementwise mask) -------
__global__ void conv_bf16(const float* __restrict__ in, const float* __restrict__ mask,
                          short* __restrict__ out, int n4)
{
    int i = blockIdx.x * blockDim.x + threadIdx.x;
    if (i >= n4) return;
    float4 v = ((const float4*)in)[i];
    if (mask) {
        float4 m = ((const float4*)mask)[i];
        v.x *= m.x; v.y *= m.y; v.z *= m.z; v.w *= m.w;
    }
    short4 o;
    o.x = f2bf(v.x); o.y = f2bf(v.y); o.z = f2bf(v.z); o.w = f2bf(v.w);
    ((short4*)out)[i] = o;
}

// ---------------- f32 -> bf16 with K-padding (for GEMM1, 168 -> 192) -------
__global__ void padconv_bf16(const float* __restrict__ in, const float* __restrict__ mask,
                             short* __restrict__ out, int M, int Kin4, int Kout4)
{
    int idx = blockIdx.x * blockDim.x + threadIdx.x;
    if (idx >= M * Kout4) return;
    int m = idx / Kout4, k4 = idx % Kout4;
    float4 v = make_float4(0.f, 0.f, 0.f, 0.f);
    if (k4 < Kin4) {
        v = ((const float4*)in)[(size_t)m * Kin4 + k4];
        if (mask) {
            float4 mm = ((const float4*)mask)[(size_t)m * Kin4 + k4];
            v.x *= mm.x; v.y *= mm.y; v.z *= mm.z; v.w *= mm.w;
        }
    }
    short4 o;
    o.x = f2bf(v.x); o.y = f2bf(v.y); o.z = f2bf(v.z); o.w = f2bf(v.w);
    ((short4*)out)[(size_t)m * Kout4 + k4] = o;
}

// ---------------- combined LSTM biases -------------------------------------
__global__ void bias_sum_kernel(const float* __restrict__ bihf, const float* __restrict__ bhhf,
                                const float* __restrict__ bihb, const float* __restrict__ bhhb,
                                float* __restrict__ o)
{
    int i = blockIdx.x * blockDim.x + threadIdx.x;
    if (i < 2048)      o[i] = bihf[i] + bhhf[i];
    else if (i < 4096) o[i] = bihb[i - 2048] + bhhb[i - 2048];
}

// ---------------- one BiLSTM time step, MFMA recurrence --------------------
// grid = 64: dir = bid>>5, jt = bid&31 (16 gate-cols per block).
// 4 waves; wave w computes gate-type w for cols j0..j0+15, all 32 batches:
// gates[32,16] = h[32,512](bf16) @ whh_rows[16,512]^T via 16x16x32 MFMA.
// Gate exchange through LDS, fused pointwise update. h ping-pong in bf16.
__global__ __launch_bounds__(256)
void lstm_step_mfma(int t,
                    const float* __restrict__ xp,   // [2048][4096] f32 (fwd|bwd gates)
                    const short* __restrict__ whb,  // [2][2048][512] bf16
                    short* __restrict__ hbuf,       // [2][2][32*512] bf16
                    float* __restrict__ cbuf,       // [2][32*512] f32
                    short* __restrict__ y,          // [32][64][1024] bf16
                    float* __restrict__ out)        // hidden/cell at t==63
{
    __shared__ short As[32 * 64];        // h tile      4 KB
    __shared__ short Bs[64 * 64];        // w tile      8 KB
    __shared__ float gbuf[4][32][17];    // gate xchg   8.7 KB

    const int bid = blockIdx.x;
    const int dir = bid >> 5;
    const int jt  = bid & 31;
    const int j0  = jt * 16;
    const int tid = threadIdx.x;
    const int l    = tid & 63;
    const int wave = tid >> 6;
    const int tt = dir ? (63 - t) : t;

    const short* hread  = hbuf + dir * 2 * 16384 + (t & 1) * 16384;
    short*       hwrite = hbuf + dir * 2 * 16384 + ((t + 1) & 1) * 16384;
    float*       cst    = cbuf + dir * 16384;
    const short* whh    = whb + (size_t)dir * 1048576;

    // staging addresses (pre-swizzled global source, rule #21)
    const int srow = tid >> 3;                    // 0..31
    const int gc   = (tid & 7) ^ (srow & 7);
    const short* gA = hread + srow * 512 + gc * 8;
    const int rt1 = 32 + srow;
    const short* gB0 = whh + ((size_t)((srow >> 4) * 512 + j0 + (srow & 15))) * 512 + gc * 8;
    const short* gB1 = whh + ((size_t)((rt1 >> 4) * 512 + j0 + (rt1 & 15))) * 512 + gc * 8;
    char* AsB = (char*)As;
    char* BsB = (char*)Bs;
    char* dstA = AsB + wave * 1024;
    char* dstB = BsB + wave * 1024;

    // fragment offsets (swizzled read side)
    int aoff[2], soff[2];
    aoff[0] = (l & 15) * 128;
    aoff[1] = (16 + (l & 15)) * 128;
    const int boff = (wave * 16 + (l & 15)) * 128;
    soff[0] = ((0 * 4 + (l >> 4)) ^ (l & 7)) * 16;
    soff[1] = ((1 * 4 + (l >> 4)) ^ (l & 7)) * 16;

    f32x4 acc0, acc1;
    acc0[0] = 0.f; acc0[1] = 0.f; acc0[2] = 0.f; acc0[3] = 0.f;
    acc1 = acc0;

    for (int kt = 0; kt < 512; kt += 64) {
        load_lds16(gA + kt, dstA);
        load_lds16(gB0 + kt, dstB);
        load_lds16(gB1 + kt, dstB + 4096);
        __syncthreads();
#pragma unroll
        for (int kh = 0; kh < 2; ++kh) {
            s16x8 bv = *(const s16x8*)(BsB + boff + soff[kh]);
            s16x8 a0 = *(const s16x8*)(AsB + aoff[0] + soff[kh]);
            s16x8 a1 = *(const s16x8*)(AsB + aoff[1] + soff[kh]);
            acc0 = __builtin_amdgcn_mfma_f32_16x16x32_bf16(a0, bv, acc0, 0, 0, 0);
            acc1 = __builtin_amdgcn_mfma_f32_16x16x32_bf16(a1, bv, acc1, 0, 0, 0);
        }
        __syncthreads();
    }

    // scatter gates to LDS: wave w holds gate w; row = batch, col = j-local
    {
        const int jl = l & 15, r4 = (l >> 4) * 4;
#pragma unroll
        for (int r = 0; r < 4; ++r) {
            gbuf[wave][r4 + r][jl]      = acc0[r];
            gbuf[wave][16 + r4 + r][jl] = acc1[r];
        }
    }
    __syncthreads();

    // fused gate math: 512 outputs, 2 per thread, j-contiguous lanes
    const int jl = tid & 15;
    const int bq = tid >> 4;           // 0..15
#pragma unroll
    for (int u = 0; u < 2; ++u) {
        const int b = bq + 16 * u;
        const int j = j0 + jl;
        const float* xprow = xp + ((size_t)(b * 64 + tt)) * 4096 + dir * 2048;
        float g_i = gbuf[0][b][jl] + xprow[0 * 512 + j];
        float g_f = gbuf[1][b][jl] + xprow[1 * 512 + j];
        float g_g = gbuf[2][b][jl] + xprow[2 * 512 + j];
        float g_o = gbuf[3][b][jl] + xprow[3 * 512 + j];

        float si = 1.f / (1.f + expf(-g_i));
        float sf = 1.f / (1.f + expf(-g_f));
        float so = 1.f / (1.f + expf(-g_o));
        float tg = tanhf(g_g);

        float c_old = cst[b * 512 + j];
        float c_new = sf * c_old + si * tg;
        float h_new = so * tanhf(c_new);

        cst[b * 512 + j]    = c_new;
        hwrite[b * 512 + j] = f2bf(h_new);
        y[((size_t)(b * 64 + tt)) * 1024 + dir * 512 + j] = f2bf(h_new);

        if (t == 63) {
            out[524288 + dir * 16384 + b * 512 + j]         = h_new;
            out[524288 + 32768 + dir * 16384 + b * 512 + j] = c_new;
        }
    }
}

// ---------------------------------------------------------------------------
extern "C" void kernel_launch(void* const* d_in, const int* in_sizes, int n_in,
                              void* d_out, int out_size, void* d_ws, size_t ws_size,
                              hipStream_t stream)
{
    const float* x     = (const float*)d_in[0];
    const float* w1    = (const float*)d_in[1];
    const float* b1    = (const float*)d_in[2];
    const float* mask1 = (const float*)d_in[3];
    const float* w2    = (const float*)d_in[4];
    const float* b2    = (const float*)d_in[5];
    const float* mask2 = (const float*)d_in[6];
    const float* wihf  = (const float*)d_in[7];
    const float* whhf  = (const float*)d_in[8];
    const float* bihf  = (const float*)d_in[9];
    const float* bhhf  = (const float*)d_in[10];
    const float* wihb  = (const float*)d_in[11];
    const float* whhb  = (const float*)d_in[12];
    const float* bihb  = (const float*)d_in[13];
    const float* bhhb  = (const float*)d_in[14];
    const float* wo1   = (const float*)d_in[15];
    const float* bo1   = (const float*)d_in[16];
    const float* wo2   = (const float*)d_in[17];
    const float* bo2   = (const float*)d_in[18];
    float* out = (float*)d_out;

    // ---- workspace regions (byte offsets), with lifetime-based aliasing ----
    // A @0        : wqb [4096x3584]bf16 (29,360,128) ; later whb [2x2048x512]bf16
    // B @29360128 : h2b [2048x3584]bf16 (14,680,064) ; earlier xpad+w1mb
    // C @44040192 : xp  [2048x4096]f32  (33,554,432) ; earlier w2b (12,845,056)
    // D @77594624 : h1b [2048x1792]bf16 (7,340,032)  ; later ybuf|o1|wo1b|wo2b
    // E @84934656 : hbuf(131072) cbuf(131072) bsum(16384)   -> total 85,213,184
    char* base = (char*)d_ws;
    short* wqb  = (short*)base;
    short* whb  = (short*)base;                       // after xproj, aliases wqb
    char*  Breg = base + 29360128;
    short* h2b  = (short*)Breg;
    short* xpad = (short*)Breg;                       // [2048][192] bf16
    short* w1mb = (short*)(Breg + 786432);            // [1792][192] bf16
    char*  Creg = base + 44040192;
    float* xp   = (float*)Creg;
    short* w2b  = (short*)Creg;                       // dead before xp written
    char*  Dreg = base + 77594624;
    short* h1b  = (short*)Dreg;
    short* ybuf = (short*)Dreg;                       // after GEMM2, aliases h1b
    short* o1   = (short*)(Dreg + 4194304);
    short* wo1b = (short*)(Dreg + 5242880);
    short* wo2b = (short*)(Dreg + 5767168);
    char*  Ereg = base + 84934656;
    short* hbuf = (short*)Ereg;
    float* cbuf = (float*)(Ereg + 131072);
    float* bsum = (float*)(Ereg + 262144);

    hipMemsetAsync(Ereg, 0, 262144, stream);   // hbuf + cbuf zeros
    bias_sum_kernel<<<16, 256, 0, stream>>>(bihf, bhhf, bihb, bhhb, bsum);

    // weight / input conversions
    conv_bf16<<<6272, 256, 0, stream>>>(w2, mask2, w2b, 6422528 / 4);
    conv_bf16<<<7168, 256, 0, stream>>>(wihf, nullptr, wqb, 7340032 / 4);
    conv_bf16<<<7168, 256, 0, stream>>>(wihb, nullptr, wqb + 7340032, 7340032 / 4);
    padconv_bf16<<<384, 256, 0, stream>>>(x, nullptr, xpad, 2048, 42, 48);
    padconv_bf16<<<336, 256, 0, stream>>>(w1, mask1, w1mb, 1792, 42, 48);

    // GEMM1 (MFMA, K padded to 192): xpad @ w1mb^T + b1, ReLU -> h1b bf16
    gemm_mfma<true, true><<<dim3(1792 / 128, 2048 / 128), 256, 0, stream>>>(
        xpad, w1mb, b1, h1b, 2048, 1792, 192);

    // GEMM2 (MFMA): h1b @ w2b^T + b2, ReLU -> h2b bf16   (frees xpad/w1mb)
    gemm_mfma<true, true><<<dim3(3584 / 128, 2048 / 128), 256, 0, stream>>>(
        h1b, w2b, b2, h2b, 2048, 3584, 1792);

    // merged LSTM input projection: h2b @ [wihf;wihb]^T + bsum -> xp f32
    // (frees w2b; xp cols: dir*2048 + gate*512 + j)
    gemm_mfma<false, false><<<dim3(4096 / 128, 2048 / 128), 256, 0, stream>>>(
        h2b, wqb, bsum, xp, 2048, 4096, 3584);

    // recurrent weights to bf16 (aliases wqb -> must follow xproj)
    conv_bf16<<<1024, 256, 0, stream>>>(whhf, nullptr, whb, 1048576 / 4);
    conv_bf16<<<1024, 256, 0, stream>>>(whhb, nullptr, whb + 1048576, 1048576 / 4);
    // head weights to bf16 (alias h1b -> after GEMM2)
    conv_bf16<<<256, 256, 0, stream>>>(wo1, nullptr, wo1b, 262144 / 4);
    conv_bf16<<<64, 256, 0, stream>>>(wo2, nullptr, wo2b, 65536 / 4);

    // 64 sequential BiLSTM steps (MFMA recurrence, both dirs fused)
    for (int t = 0; t < 64; ++t)
        lstm_step_mfma<<<64, 256, 0, stream>>>(t, xp, whb, hbuf, cbuf, ybuf, out);

    // output head (MFMA): ReLU(y @ wo1^T + bo1) @ wo2^T + bo2 -> out f32
    gemm_mfma<true, true><<<dim3(256 / 128, 2048 / 128), 256, 0, stream>>>(
        ybuf, wo1b, bo1, o1, 2048, 256, 1024);
    gemm_mfma<false, false><<<dim3(256 / 128, 2048 / 128), 256, 0, stream>>>(
        o1, wo2b, bo2, out, 2048, 256, 256);
}